// Round 1
// baseline (204.101 us; speedup 1.0000x reference)
//
#include <hip/hip_runtime.h>

// DropConnect training path:
//   y[n,o] = 2 * ( sum_k x[n,k]*W[k,o]*wm[n,k,o] + b[o]*bm[n,o] )
// N=256, IN_DIM=1024, OUT_DIM=1024. Memory-bound on w_mask (1.07 GB, read once).

constexpr int N_      = 256;
constexpr int IN_DIM  = 1024;
constexpr int OUT_DIM = 1024;

typedef float f32x4 __attribute__((ext_vector_type(4)));

__global__ __launch_bounds__(256, 4) void dropconnect_kernel(
    const float* __restrict__ x,       // [N, IN_DIM]
    const float* __restrict__ weight,  // [IN_DIM, OUT_DIM]
    const float* __restrict__ bias,    // [OUT_DIM]
    const float* __restrict__ w_mask,  // [N, IN_DIM, OUT_DIM]
    const float* __restrict__ b_mask,  // [N, OUT_DIM]
    float* __restrict__ out)           // [N, OUT_DIM]
{
    const int n = blockIdx.x;          // one block per sample
    const int t = threadIdx.x;         // 0..255 -> float4 column group

    const size_t row4 = (size_t)n * IN_DIM * (OUT_DIM / 4);
    const f32x4* __restrict__ wm = reinterpret_cast<const f32x4*>(w_mask) + row4 + t;
    const f32x4* __restrict__ wt = reinterpret_cast<const f32x4*>(weight) + t;
    const float* __restrict__ xr = x + n * IN_DIM;

    f32x4 acc = {0.f, 0.f, 0.f, 0.f};

    #pragma unroll 8
    for (int k = 0; k < IN_DIM; ++k) {
        const float xv = xr[k];                              // block-uniform -> s_load
        const f32x4 m = __builtin_nontemporal_load(wm + (size_t)k * (OUT_DIM / 4));
        const f32x4 w = wt[k * (OUT_DIM / 4)];               // L2-resident
        acc[0] = fmaf(xv * w[0], m[0], acc[0]);
        acc[1] = fmaf(xv * w[1], m[1], acc[1]);
        acc[2] = fmaf(xv * w[2], m[2], acc[2]);
        acc[3] = fmaf(xv * w[3], m[3], acc[3]);
    }

    const f32x4 bm = reinterpret_cast<const f32x4*>(b_mask)[n * (OUT_DIM / 4) + t];
    const f32x4 bs = reinterpret_cast<const f32x4*>(bias)[t];
    f32x4 r;
    r[0] = 2.0f * (acc[0] + bs[0] * bm[0]);
    r[1] = 2.0f * (acc[1] + bs[1] * bm[1]);
    r[2] = 2.0f * (acc[2] + bs[2] * bm[2]);
    r[3] = 2.0f * (acc[3] + bs[3] * bm[3]);
    reinterpret_cast<f32x4*>(out)[n * (OUT_DIM / 4) + t] = r;
}

extern "C" void kernel_launch(void* const* d_in, const int* in_sizes, int n_in,
                              void* d_out, int out_size, void* d_ws, size_t ws_size,
                              hipStream_t stream) {
    const float* x      = (const float*)d_in[0];
    const float* weight = (const float*)d_in[1];
    const float* bias   = (const float*)d_in[2];
    const float* w_mask = (const float*)d_in[3];
    const float* b_mask = (const float*)d_in[4];
    float* out = (float*)d_out;

    dim3 grid(N_);
    dim3 block(256);
    dropconnect_kernel<<<grid, block, 0, stream>>>(x, weight, bias, w_mask, b_mask, out);
}

// Round 2
// 187.014 us; speedup vs baseline: 1.0914x; 1.0914x over previous
//
#include <hip/hip_runtime.h>

// DropConnect training path:
//   y[n,o] = 2 * ( sum_k x[n,k]*W[k,o]*wm[n,k,o] + b[o]*bm[n,o] )
// N=256, IN_DIM=1024, OUT_DIM=1024. Memory-bound on w_mask (1.07 GB, read once).
//
// R2: k-split-in-block. 1024-thread blocks (16 waves/CU vs 4 before) — each
// of 4 k-quarters accumulates a per-thread f32x4 partial; LDS tree-sum at end.
// Raises occupancy 12%->50% to hide HBM latency; coalescing unchanged.

constexpr int N_      = 256;
constexpr int IN_DIM  = 1024;
constexpr int OUT_DIM = 1024;
constexpr int O4      = OUT_DIM / 4;   // 256 float4 columns
constexpr int KSPLIT  = 4;
constexpr int KCHUNK  = IN_DIM / KSPLIT; // 256

typedef float f32x4 __attribute__((ext_vector_type(4)));

__global__ __launch_bounds__(1024, 4) void dropconnect_kernel(
    const float* __restrict__ x,       // [N, IN_DIM]
    const float* __restrict__ weight,  // [IN_DIM, OUT_DIM]
    const float* __restrict__ bias,    // [OUT_DIM]
    const float* __restrict__ w_mask,  // [N, IN_DIM, OUT_DIM]
    const float* __restrict__ b_mask,  // [N, OUT_DIM]
    float* __restrict__ out)           // [N, OUT_DIM]
{
    __shared__ f32x4 red[1024];        // 16 KB

    const int n  = blockIdx.x;         // one block per sample
    const int t  = threadIdx.x;        // 0..1023
    const int ks = t >> 8;             // k-quarter 0..3 (wave-uniform)
    const int c4 = t & 255;            // float4 column group 0..255

    const size_t base4 = ((size_t)n * IN_DIM + (size_t)ks * KCHUNK) * O4;
    const f32x4* __restrict__ wm = reinterpret_cast<const f32x4*>(w_mask) + base4 + c4;
    const f32x4* __restrict__ wt = reinterpret_cast<const f32x4*>(weight) + (size_t)ks * KCHUNK * O4 + c4;
    const float* __restrict__ xr = x + n * IN_DIM + ks * KCHUNK;

    f32x4 acc = {0.f, 0.f, 0.f, 0.f};

    #pragma unroll 8
    for (int k = 0; k < KCHUNK; ++k) {
        const float xv = xr[k];                               // wave-uniform -> s_load
        const f32x4 m = __builtin_nontemporal_load(wm + (size_t)k * O4);
        const f32x4 w = wt[k * O4];                           // L2-resident
        acc[0] = fmaf(xv * w[0], m[0], acc[0]);
        acc[1] = fmaf(xv * w[1], m[1], acc[1]);
        acc[2] = fmaf(xv * w[2], m[2], acc[2]);
        acc[3] = fmaf(xv * w[3], m[3], acc[3]);
    }

    red[t] = acc;
    __syncthreads();

    if (t < 256) {
        const f32x4 a0 = red[t];
        const f32x4 a1 = red[t + 256];
        const f32x4 a2 = red[t + 512];
        const f32x4 a3 = red[t + 768];

        const f32x4 bm = reinterpret_cast<const f32x4*>(b_mask)[n * O4 + t];
        const f32x4 bs = reinterpret_cast<const f32x4*>(bias)[t];
        f32x4 r;
        r[0] = 2.0f * ((a0[0] + a1[0]) + (a2[0] + a3[0]) + bs[0] * bm[0]);
        r[1] = 2.0f * ((a0[1] + a1[1]) + (a2[1] + a3[1]) + bs[1] * bm[1]);
        r[2] = 2.0f * ((a0[2] + a1[2]) + (a2[2] + a3[2]) + bs[2] * bm[2]);
        r[3] = 2.0f * ((a0[3] + a1[3]) + (a2[3] + a3[3]) + bs[3] * bm[3]);
        reinterpret_cast<f32x4*>(out)[n * O4 + t] = r;
    }
}

extern "C" void kernel_launch(void* const* d_in, const int* in_sizes, int n_in,
                              void* d_out, int out_size, void* d_ws, size_t ws_size,
                              hipStream_t stream) {
    const float* x      = (const float*)d_in[0];
    const float* weight = (const float*)d_in[1];
    const float* bias   = (const float*)d_in[2];
    const float* w_mask = (const float*)d_in[3];
    const float* b_mask = (const float*)d_in[4];
    float* out = (float*)d_out;

    dim3 grid(N_);
    dim3 block(KSPLIT * 256);
    dropconnect_kernel<<<grid, block, 0, stream>>>(x, weight, bias, w_mask, b_mask, out);
}

// Round 3
// 185.627 us; speedup vs baseline: 1.0995x; 1.0075x over previous
//
#include <hip/hip_runtime.h>

// DropConnect training path:
//   y[n,o] = 2 * ( sum_k x[n,k]*W[k,o]*wm[n,k,o] + b[o]*bm[n,o] )
// N=256, IN_DIM=1024, OUT_DIM=1024. Memory-bound on w_mask (1.07 GB, read once).
//
// R3: finer decomposition. grid=512 (2 blocks/CU), block=512 (8 waves).
// Block (bid) owns sample n=bid>>1, o-half bid&1 (128 f32x4 columns), k-split 4.
// Two independent blocks per CU: one block's barrier/reduce/epilogue overlaps the
// other's streaming; halves tail imbalance. Coalescing unchanged (1KB/wave-load).

constexpr int N_      = 256;
constexpr int IN_DIM  = 1024;
constexpr int OUT_DIM = 1024;
constexpr int O4      = OUT_DIM / 4;     // 256 float4 columns per sample
constexpr int OH4     = O4 / 2;          // 128 float4 columns per block
constexpr int KSPLIT  = 4;
constexpr int KCHUNK  = IN_DIM / KSPLIT; // 256

typedef float f32x4 __attribute__((ext_vector_type(4)));

__global__ __launch_bounds__(512, 4) void dropconnect_kernel(
    const float* __restrict__ x,       // [N, IN_DIM]
    const float* __restrict__ weight,  // [IN_DIM, OUT_DIM]
    const float* __restrict__ bias,    // [OUT_DIM]
    const float* __restrict__ w_mask,  // [N, IN_DIM, OUT_DIM]
    const float* __restrict__ b_mask,  // [N, OUT_DIM]
    float* __restrict__ out)           // [N, OUT_DIM]
{
    __shared__ f32x4 red[512];         // 8 KB

    const int bid = blockIdx.x;
    const int n   = bid >> 1;          // sample
    const int oh  = bid & 1;           // o-half
    const int t   = threadIdx.x;       // 0..511
    const int ks  = t >> 7;            // k-quarter 0..3 (wave-uniform)
    const int c4  = (t & 127) + oh * OH4;  // float4 column 0..255

    const size_t base4 = ((size_t)n * IN_DIM + (size_t)ks * KCHUNK) * O4;
    const f32x4* __restrict__ wm = reinterpret_cast<const f32x4*>(w_mask) + base4 + c4;
    const f32x4* __restrict__ wt = reinterpret_cast<const f32x4*>(weight) + (size_t)ks * KCHUNK * O4 + c4;
    const float* __restrict__ xr = x + n * IN_DIM + ks * KCHUNK;

    f32x4 acc = {0.f, 0.f, 0.f, 0.f};

    #pragma unroll 8
    for (int k = 0; k < KCHUNK; ++k) {
        const float xv = xr[k];                               // wave-uniform
        const f32x4 m = __builtin_nontemporal_load(wm + (size_t)k * O4);
        const f32x4 w = wt[k * O4];                           // L2-resident
        acc[0] = fmaf(xv * w[0], m[0], acc[0]);
        acc[1] = fmaf(xv * w[1], m[1], acc[1]);
        acc[2] = fmaf(xv * w[2], m[2], acc[2]);
        acc[3] = fmaf(xv * w[3], m[3], acc[3]);
    }

    red[t] = acc;
    __syncthreads();

    if (t < 128) {
        const f32x4 a0 = red[t];
        const f32x4 a1 = red[t + 128];
        const f32x4 a2 = red[t + 256];
        const f32x4 a3 = red[t + 384];

        const int oc = oh * OH4 + t;   // this thread's float4 column
        const f32x4 bm = reinterpret_cast<const f32x4*>(b_mask)[n * O4 + oc];
        const f32x4 bs = reinterpret_cast<const f32x4*>(bias)[oc];
        f32x4 r;
        r[0] = 2.0f * ((a0[0] + a1[0]) + (a2[0] + a3[0]) + bs[0] * bm[0]);
        r[1] = 2.0f * ((a0[1] + a1[1]) + (a2[1] + a3[1]) + bs[1] * bm[1]);
        r[2] = 2.0f * ((a0[2] + a1[2]) + (a2[2] + a3[2]) + bs[2] * bm[2]);
        r[3] = 2.0f * ((a0[3] + a1[3]) + (a2[3] + a3[3]) + bs[3] * bm[3]);
        reinterpret_cast<f32x4*>(out)[n * O4 + oc] = r;
    }
}

extern "C" void kernel_launch(void* const* d_in, const int* in_sizes, int n_in,
                              void* d_out, int out_size, void* d_ws, size_t ws_size,
                              hipStream_t stream) {
    const float* x      = (const float*)d_in[0];
    const float* weight = (const float*)d_in[1];
    const float* bias   = (const float*)d_in[2];
    const float* w_mask = (const float*)d_in[3];
    const float* b_mask = (const float*)d_in[4];
    float* out = (float*)d_out;

    dim3 grid(N_ * 2);
    dim3 block(512);
    dropconnect_kernel<<<grid, block, 0, stream>>>(x, weight, bias, w_mask, b_mask, out);
}

// Round 4
// 182.164 us; speedup vs baseline: 1.1204x; 1.0190x over previous
//
#include <hip/hip_runtime.h>

// DropConnect training path:
//   y[n,o] = 2 * ( sum_k x[n,k]*W[k,o]*wm[n,k,o] + b[o]*bm[n,o] )
// N=256, IN_DIM=1024, OUT_DIM=1024. Memory-bound on w_mask (1.07 GB, read once).
//
// R4: max TLP. block=256 (4 waves; wave = k-quarter, lane = f32x4 column),
// grid=1024 (sample x o-quarter). __launch_bounds__(256,8) caps VGPR at 64 ->
// 32 waves/CU (100% occupancy), 8 independent blocks/CU. Unroll 4 (not 8) so
// the body fits 64 VGPR without spill; TLP replaces the lost ILP.

constexpr int N_      = 256;
constexpr int IN_DIM  = 1024;
constexpr int OUT_DIM = 1024;
constexpr int O4      = OUT_DIM / 4;     // 256 float4 columns per sample
constexpr int OQ4     = O4 / 4;          // 64 float4 columns per block
constexpr int KSPLIT  = 4;
constexpr int KCHUNK  = IN_DIM / KSPLIT; // 256

typedef float f32x4 __attribute__((ext_vector_type(4)));

__global__ __launch_bounds__(256, 8) void dropconnect_kernel(
    const float* __restrict__ x,       // [N, IN_DIM]
    const float* __restrict__ weight,  // [IN_DIM, OUT_DIM]
    const float* __restrict__ bias,    // [OUT_DIM]
    const float* __restrict__ w_mask,  // [N, IN_DIM, OUT_DIM]
    const float* __restrict__ b_mask,  // [N, OUT_DIM]
    float* __restrict__ out)           // [N, OUT_DIM]
{
    __shared__ f32x4 red[256];         // 4 KB

    const int bid = blockIdx.x;
    const int n   = bid >> 2;          // sample
    const int oq  = bid & 3;           // o-quarter
    const int t   = threadIdx.x;       // 0..255
    const int ks  = t >> 6;            // k-quarter 0..3 == wave id (wave-uniform)
    const int c4  = (t & 63) + oq * OQ4;   // float4 column 0..255

    const size_t base4 = ((size_t)n * IN_DIM + (size_t)ks * KCHUNK) * O4;
    const f32x4* __restrict__ wm = reinterpret_cast<const f32x4*>(w_mask) + base4 + c4;
    const f32x4* __restrict__ wt = reinterpret_cast<const f32x4*>(weight) + (size_t)ks * KCHUNK * O4 + c4;
    const float* __restrict__ xr = x + n * IN_DIM + ks * KCHUNK;

    f32x4 acc = {0.f, 0.f, 0.f, 0.f};

    #pragma unroll 4
    for (int k = 0; k < KCHUNK; ++k) {
        const float xv = xr[k];                               // wave-uniform
        const f32x4 m = __builtin_nontemporal_load(wm + (size_t)k * O4);
        const f32x4 w = wt[k * O4];                           // L2-resident
        acc[0] = fmaf(xv * w[0], m[0], acc[0]);
        acc[1] = fmaf(xv * w[1], m[1], acc[1]);
        acc[2] = fmaf(xv * w[2], m[2], acc[2]);
        acc[3] = fmaf(xv * w[3], m[3], acc[3]);
    }

    red[t] = acc;
    __syncthreads();

    if (t < 64) {
        const f32x4 a0 = red[t];
        const f32x4 a1 = red[t + 64];
        const f32x4 a2 = red[t + 128];
        const f32x4 a3 = red[t + 192];

        const int oc = oq * OQ4 + t;   // this thread's float4 column
        const f32x4 bm = reinterpret_cast<const f32x4*>(b_mask)[n * O4 + oc];
        const f32x4 bs = reinterpret_cast<const f32x4*>(bias)[oc];
        f32x4 r;
        r[0] = 2.0f * ((a0[0] + a1[0]) + (a2[0] + a3[0]) + bs[0] * bm[0]);
        r[1] = 2.0f * ((a0[1] + a1[1]) + (a2[1] + a3[1]) + bs[1] * bm[1]);
        r[2] = 2.0f * ((a0[2] + a1[2]) + (a2[2] + a3[2]) + bs[2] * bm[2]);
        r[3] = 2.0f * ((a0[3] + a1[3]) + (a2[3] + a3[3]) + bs[3] * bm[3]);
        reinterpret_cast<f32x4*>(out)[n * O4 + oc] = r;
    }
}

extern "C" void kernel_launch(void* const* d_in, const int* in_sizes, int n_in,
                              void* d_out, int out_size, void* d_ws, size_t ws_size,
                              hipStream_t stream) {
    const float* x      = (const float*)d_in[0];
    const float* weight = (const float*)d_in[1];
    const float* bias   = (const float*)d_in[2];
    const float* w_mask = (const float*)d_in[3];
    const float* b_mask = (const float*)d_in[4];
    float* out = (float*)d_out;

    dim3 grid(N_ * 4);
    dim3 block(256);
    dropconnect_kernel<<<grid, block, 0, stream>>>(x, weight, bias, w_mask, b_mask, out);
}